// Round 21
// baseline (74.396 us; speedup 1.0000x reference)
//
#include <hip/hip_runtime.h>
#include <hip/hip_fp16.h>
#include <math.h>

#define LQ 5440
#define LV 5440
#define BATCH_ 4
#define M_TOT (BATCH_ * LQ)   // 21760

typedef _Float16 f16x8 __attribute__((ext_vector_type(8)));
typedef _Float16 f16x2t __attribute__((ext_vector_type(2)));
typedef float f32x4 __attribute__((ext_vector_type(4)));
typedef unsigned int uint_t;

__device__ __forceinline__ uint_t f2h2(float a, float b) {   // pack 2 f32 -> f16x2 (RNE)
  const unsigned short ua = __half_as_ushort(__float2half(a));
  const unsigned short ub = __half_as_ushort(__float2half(b));
  return (uint_t)ua | ((uint_t)ub << 16);
}
__device__ __forceinline__ uint_t pkrtz(float a, float b) {  // HW packed f32->f16 (RTZ)
  auto r = __builtin_amdgcn_cvt_pkrtz(a, b);
  uint_t u;
  __builtin_memcpy(&u, &r, 4);
  return u;
}
__device__ __forceinline__ float lo_f(uint_t u) {
  f16x2t h; __builtin_memcpy(&h, &u, 4); return (float)h[0];
}
__device__ __forceinline__ float hi_f(uint_t u) {
  f16x2t h; __builtin_memcpy(&h, &u, 4); return (float)h[1];
}

// ---------------- weight conversion (transpose + f16) + valb guard zeroing ----------------
__global__ __launch_bounds__(256) void conv_weights(
    const float* __restrict__ w_off, const float* __restrict__ w_out,
    const float* __restrict__ w_val, const float* __restrict__ w_attn,
    unsigned short* __restrict__ Wcat, unsigned short* __restrict__ Wo,
    unsigned short* __restrict__ Wvt,
    unsigned short* __restrict__ guard_pre, unsigned short* __restrict__ guard_post)
{
  __shared__ float tbuf[64][65];
  const int tid = threadIdx.x;
  if (blockIdx.x == 0 && blockIdx.y == 0 && tid < 64) {
    guard_pre[tid] = 0;
    guard_post[tid] = 0;
  }
  const int k0 = blockIdx.x * 64;
  const int yy = blockIdx.y;
  const float* src; unsigned short* dst; int N; int ntile; int roff = 0;
  if (yy < 4)       { src = w_off;  dst = Wcat; N = 256; ntile = yy; }
  else if (yy < 8)  { src = w_out;  dst = Wo;   N = 256; ntile = yy - 4; }
  else if (yy < 12) { src = w_val;  dst = Wvt;  N = 256; ntile = yy - 8; }
  else              { src = w_attn; dst = Wcat; N = 128; ntile = yy - 12; roff = 256; }
  const int n0 = ntile * 64;
#pragma unroll
  for (int i = 0; i < 16; ++i) {
    const int r = (tid >> 6) + i * 4;
    const int c = tid & 63;
    tbuf[r][c] = src[(size_t)(k0 + r) * N + n0 + c];
  }
  __syncthreads();
#pragma unroll
  for (int i = 0; i < 16; ++i) {
    const int n = (tid >> 6) + i * 4;
    const int kk = tid & 63;
    dst[(size_t)(roff + n0 + n) * 256 + k0 + kk] =
        __half_as_ushort(__float2half(tbuf[kk][n]));
  }
}

// ---------------- front GEMM: value(head-major out) + off/logit fused, XCD-grouped ----------
__global__ __launch_bounds__(256) void gemm_front(
    const float* __restrict__ ifl, const float* __restrict__ query,
    const unsigned short* __restrict__ Wvt, const unsigned short* __restrict__ Wcat,
    const float* __restrict__ b_val, const float* __restrict__ b_off,
    const float* __restrict__ b_attn,
    unsigned short* __restrict__ valb, unsigned short* __restrict__ offb,
    unsigned short* __restrict__ logitb)
{
  const int P = blockIdx.x;
  const int X = P & 7;
  const int j = P >> 3;
  const int p = j % 5;
  const int rblk = X * 22 + j / 5;
  if (rblk >= M_TOT / 128) return;

  __shared__ unsigned short Sh[2][128 * 64];
  unsigned short* As = Sh[0];
  unsigned short* Bs = Sh[1];
  const int tid = threadIdx.x;
  const int w = tid >> 6, lane = tid & 63;
  const int wm = w >> 1, wn = w & 1;
  const int lr = lane & 15, lk = lane >> 4;
  const bool isval = p < 2;
  const float* Af = isval ? ifl : query;
  const unsigned short* Bt = isval ? Wvt : Wcat;
  const int n0 = (isval ? p : p - 2) * 128;
  const int m0 = rblk * 128;

  f32x4 acc[4][4] = {};

  for (int t = 0; t < 4; ++t) {
    const int ka = t * 64;
#pragma unroll
    for (int i = 0; i < 4; ++i) {
      const int rbase = i * 32 + w * 8;
      const int row = rbase + (lane >> 3);
      const int slot = lane & 7;
      const int gs = slot ^ (row & 7);                 // inverse-swizzle SOURCE (rule 21)
      const unsigned short* gp = Bt + (size_t)(n0 + row) * 256 + ka + gs * 8;
      __builtin_amdgcn_global_load_lds(
          (const __attribute__((address_space(1))) uint_t*)gp,
          (__attribute__((address_space(3))) uint_t*)(Bs + rbase * 64), 16, 0, 0);
    }
#pragma unroll
    for (int i = 0; i < 4; ++i) {
      const int rbase = i * 32 + w * 8;
      const int row = rbase + (lane >> 3);
      const int slot = lane & 7;
      const int gs = slot ^ (row & 7);
      const float* gp = Af + (size_t)(m0 + row) * 256 + ka + gs * 8;
      const float4 a0 = *(const float4*)gp;
      const float4 a1 = *(const float4*)(gp + 4);
      *(uint4*)&As[(size_t)row * 64 + slot * 8] =
          make_uint4(pkrtz(a0.x, a0.y), pkrtz(a0.z, a0.w),
                     pkrtz(a1.x, a1.y), pkrtz(a1.z, a1.w));
    }
    asm volatile("s_waitcnt vmcnt(0)" ::: "memory");
    __syncthreads();
#pragma unroll
    for (int kk = 0; kk < 2; ++kk) {
      f16x8 af[4], bfv[4];
#pragma unroll
      for (int m = 0; m < 4; ++m) {
        const int row = wm * 64 + m * 16 + lr;
        const int so = (kk * 4 + lk) ^ (row & 7);      // swizzled read
        af[m] = *(const f16x8*)((const char*)As + row * 128 + so * 16);
      }
#pragma unroll
      for (int n = 0; n < 4; ++n) {
        const int row = wn * 64 + n * 16 + lr;
        const int so = (kk * 4 + lk) ^ (row & 7);
        bfv[n] = *(const f16x8*)((const char*)Bs + row * 128 + so * 16);
      }
#pragma unroll
      for (int m = 0; m < 4; ++m)
#pragma unroll
        for (int n = 0; n < 4; ++n)
          acc[m][n] = __builtin_amdgcn_mfma_f32_16x16x32_f16(af[m], bfv[n], acc[m][n], 0, 0, 0);
    }
    __syncthreads();
  }

  if (!isval) {
#pragma unroll
    for (int n = 0; n < 4; ++n) {
      const int col = n0 + wn * 64 + n * 16 + lr;
      const float bv = (col < 256) ? b_off[col] : b_attn[col - 256];
#pragma unroll
      for (int m = 0; m < 4; ++m) {
        const int rbase = m0 + wm * 64 + m * 16 + lk * 4;
#pragma unroll
        for (int j2 = 0; j2 < 4; ++j2) {
          const float v = acc[m][n][j2] + bv;
          const int row = rbase + j2;
          const unsigned short hv = __half_as_ushort(__float2half(v));
          if (col < 256) offb[(size_t)row * 256 + col] = hv;
          else           logitb[(size_t)row * 128 + (col - 256)] = hv;
        }
      }
    }
  } else {
    // head-major epilogue via LDS transpose
    unsigned short* Sb = &Sh[0][0];                 // 32 KB
#pragma unroll
    for (int n = 0; n < 4; ++n) {
      const int lcol = wn * 64 + n * 16 + lr;
      const float bv = b_val[n0 + lcol];
#pragma unroll
      for (int m = 0; m < 4; ++m) {
        const int lrow = wm * 64 + m * 16 + lk * 4;
#pragma unroll
        for (int j2 = 0; j2 < 4; ++j2)
          Sb[(size_t)(lrow + j2) * 128 + lcol] =
              __half_as_ushort(__float2half(acc[m][n][j2] + bv));
      }
    }
    __syncthreads();
#pragma unroll
    for (int it = 0; it < 8; ++it) {
      const int idx = it * 256 + tid;
      const int r  = idx >> 4;
      const int c8 = idx & 15;
      const uint_t row_g = (uint_t)(m0 + r);
      const uint_t bb  = row_g / (uint_t)LV;
      const uint_t pos = row_g - bb * (uint_t)LV;
      const int colg = n0 + c8 * 8;
      const uint_t hh = (uint_t)colg >> 5;
      const uint_t ch = (uint_t)colg & 31u;
      unsigned short* dp = valb + (((size_t)(bb * 8u + hh) * LV + pos) << 5) + ch;
      *(uint4*)dp = *(const uint4*)&Sb[(size_t)r * 128 + c8 * 8];
    }
  }
}

// ---------------- out GEMM: BM=64 x BN=128, 680 blocks, XCD-chunked ----------------
__global__ __launch_bounds__(256) void gemm_out64(
    const unsigned short* __restrict__ A,    // samp f16 [M,256]
    const unsigned short* __restrict__ Bt,   // Wo f16 [256][256]
    const float* __restrict__ bias,
    float* __restrict__ C)
{
  const int P = blockIdx.x;
  const int G = (P & 7) * 85 + (P >> 3);
  const int p = G & 1;
  const int rblk = G >> 1;

  __shared__ unsigned short As[64 * 64];
  __shared__ unsigned short Bs[128 * 64];
  const int tid = threadIdx.x;
  const int w = tid >> 6, lane = tid & 63;
  const int wm = w & 1, wn = w >> 1;         // wave tile: 32 rows x 64 cols
  const int lr = lane & 15, lk = lane >> 4;
  const int m0 = rblk * 64, n0 = p * 128;

  f32x4 acc[2][4] = {};

  for (int t = 0; t < 4; ++t) {
    const int ka = t * 64;
#pragma unroll
    for (int i = 0; i < 2; ++i) {
      const int rbase = i * 32 + w * 8;
      const int row = rbase + (lane >> 3);
      const int slot = lane & 7;
      const int gs = slot ^ (row & 7);
      const unsigned short* gp = A + (size_t)(m0 + row) * 256 + ka + gs * 8;
      __builtin_amdgcn_global_load_lds(
          (const __attribute__((address_space(1))) uint_t*)gp,
          (__attribute__((address_space(3))) uint_t*)(As + rbase * 64), 16, 0, 0);
    }
#pragma unroll
    for (int i = 0; i < 4; ++i) {
      const int rbase = i * 32 + w * 8;
      const int row = rbase + (lane >> 3);
      const int slot = lane & 7;
      const int gs = slot ^ (row & 7);
      const unsigned short* gp = Bt + (size_t)(n0 + row) * 256 + ka + gs * 8;
      __builtin_amdgcn_global_load_lds(
          (const __attribute__((address_space(1))) uint_t*)gp,
          (__attribute__((address_space(3))) uint_t*)(Bs + rbase * 64), 16, 0, 0);
    }
    asm volatile("s_waitcnt vmcnt(0)" ::: "memory");
    __syncthreads();
#pragma unroll
    for (int kk = 0; kk < 2; ++kk) {
      f16x8 af[2], bfv[4];
#pragma unroll
      for (int m = 0; m < 2; ++m) {
        const int row = wm * 32 + m * 16 + lr;
        const int so = (kk * 4 + lk) ^ (row & 7);
        af[m] = *(const f16x8*)((const char*)As + row * 128 + so * 16);
      }
#pragma unroll
      for (int n = 0; n < 4; ++n) {
        const int row = wn * 64 + n * 16 + lr;
        const int so = (kk * 4 + lk) ^ (row & 7);
        bfv[n] = *(const f16x8*)((const char*)Bs + row * 128 + so * 16);
      }
#pragma unroll
      for (int m = 0; m < 2; ++m)
#pragma unroll
        for (int n = 0; n < 4; ++n)
          acc[m][n] = __builtin_amdgcn_mfma_f32_16x16x32_f16(af[m], bfv[n], acc[m][n], 0, 0, 0);
    }
    __syncthreads();
  }
#pragma unroll
  for (int n = 0; n < 4; ++n) {
    const int col = n0 + wn * 64 + n * 16 + lr;
    const float bv = bias[col];
#pragma unroll
    for (int m = 0; m < 2; ++m) {
      const int rbase = m0 + wm * 32 + m * 16 + lk * 4;
#pragma unroll
      for (int j2 = 0; j2 < 4; ++j2)
        C[(size_t)(rbase + j2) * 256 + col] = acc[m][n][j2] + bv;
    }
  }
}

// ---------------- sampler v18: v17 + interleaved dual-group phase 2 (2x MLP) --------
// The two gather groups per thread run point-by-point INTERLEAVED: each iteration
// issues 4 independent 128B-pair loads before any fma consumes them -> doubles
// outstanding vmem requests at constant occupancy (latency hiding via ILP).
__global__ __launch_bounds__(256) void msda_sample_v18(
    const unsigned short* __restrict__ off_buf,   // [M,256] f16
    const unsigned short* __restrict__ logit_buf, // [M,128] f16
    const unsigned short* __restrict__ value,     // [B*8][LV][32] f16
    const float* __restrict__ ref_pts,            // [B,LQ,4,2]
    const int*  __restrict__ sshapes, const int* __restrict__ lstart,
    unsigned short* __restrict__ samp)            // [M,256] f16
{
  __shared__ uint_t wlds[64 * 68];                // 17,408 B
  const int tid = threadIdx.x;
  const int P  = blockIdx.x;
  const int L  = (((P & 7) >> 1) * 680) + ((P & 1) * 340) + (P >> 3);
  const int q0 = L * 8;
  const int b  = L / (LQ / 8);

  // ---------- phase 1: 256 tasks = (q0..q7, h, l), one per thread ----------
  {
    const int q  = tid >> 5;
    const int h  = (tid >> 2) & 7;
    const int l  = tid & 3;
    const int qg = q0 + q;
    const int Hl = sshapes[2 * l], Wl = sshapes[2 * l + 1];
    const int st = lstart[l];
    const float rx = ref_pts[(size_t)qg * 8 + l * 2 + 0];
    const float ry = ref_pts[(size_t)qg * 8 + l * 2 + 1];
    const float fx = rx * (float)Wl - 0.5f;
    const float fy = ry * (float)Hl - 0.5f;

    const uint4 og = *(const uint4*)(off_buf + (size_t)qg * 256 + h * 32 + l * 8);
    const float offv[8] = {lo_f(og.x), hi_f(og.x), lo_f(og.y), hi_f(og.y),
                           lo_f(og.z), hi_f(og.z), lo_f(og.w), hi_f(og.w)};

    const uint2 lgu = *(const uint2*)(logit_buf + (size_t)qg * 128 + h * 16 + l * 4);
    float lg[4];
    lg[0] = lo_f(lgu.x); lg[1] = hi_f(lgu.x);
    lg[2] = lo_f(lgu.y); lg[3] = hi_f(lgu.y);

    float mx = fmaxf(fmaxf(lg[0], lg[1]), fmaxf(lg[2], lg[3]));
    mx = fmaxf(mx, __shfl_xor(mx, 1));
    mx = fmaxf(mx, __shfl_xor(mx, 2));
    float ex[4]; float ssum = 0.f;
#pragma unroll
    for (int p = 0; p < 4; ++p) { ex[p] = __expf(lg[p] - mx); ssum += ex[p]; }
    ssum += __shfl_xor(ssum, 1);
    ssum += __shfl_xor(ssum, 2);
    const float inv = 1.f / ssum;

    uint_t* wrow = wlds + (size_t)(q * 8 + h) * 68;

#pragma unroll
    for (int p = 0; p < 4; ++p) {
      const float x = fx + offv[p * 2 + 0];
      const float y = fy + offv[p * 2 + 1];
      const float aw = ex[p] * inv;
      const float xf = floorf(x), yf = floorf(y);
      const int x0i = (int)xf, y0i = (int)yf;
      const float wx1 = x - xf, wy1 = y - yf;
      const float wx0 = 1.f - wx1, wy0 = 1.f - wy1;
      const int x1i = x0i + 1, y1i = y0i + 1;
      const bool vx0 = (uint_t)x0i < (uint_t)Wl, vx1 = (uint_t)x1i < (uint_t)Wl;
      const bool vy0 = (uint_t)y0i < (uint_t)Hl, vy1 = (uint_t)y1i < (uint_t)Hl;
      const float awy0 = aw * wy0, awy1 = aw * wy1;
      const float w00 = (vy0 && vx0) ? awy0 * wx0 : 0.f;
      const float w01 = (vy0 && vx1) ? awy0 * wx1 : 0.f;
      const float w10 = (vy1 && vx0) ? awy1 * wx0 : 0.f;
      const float w11 = (vy1 && vx1) ? awy1 * wx1 : 0.f;
      const int yc0 = min(max(y0i, 0), Hl - 1);
      const int yc1 = min(max(y1i, 0), Hl - 1);
      const int xr  = (vx0 || vx1) ? max(x0i, -1) : 0;
      const int i00 = st + yc0 * Wl + xr;          // in [-1, LV-1]
      const int i10 = st + yc1 * Wl + xr;
      uint4 pk;
      pk.x = f2h2(w00, w01);
      pk.y = f2h2(w10, w11);
      pk.z = ((uint_t)i00 & 0xffffu) | (((uint_t)i10 & 0xffffu) << 16);
      pk.w = 0u;
      *(uint4*)(wrow + (l * 4 + p) * 4) = pk;
    }
  }
  __syncthreads();

  // ---------- phase 2: two groups per thread, point-interleaved (2x outstanding loads) ----
  {
    const int g    = tid & 7;
    const int side = g >> 2;
    const int g0i  = tid >> 3;                     // group A: 0..31
    const int g1i  = 32 + (tid >> 3);              // group B: 32..63
    const uint_t* wrowA = wlds + (size_t)g0i * 68;
    const uint_t* wrowB = wlds + (size_t)g1i * 68;
    const char* vBA = (const char*)value
        + ((size_t)(b * 8 + (g0i & 7)) * LV) * 64 + (size_t)g * 16;
    const char* vBB = (const char*)value
        + ((size_t)(b * 8 + (g1i & 7)) * LV) * 64 + (size_t)g * 16;
    float accA[8] = {}, accB[8] = {};

#pragma unroll
    for (int pt = 0; pt < 16; ++pt) {
      const uint4 pkA = *(const uint4*)(wrowA + pt * 4);
      const uint4 pkB = *(const uint4*)(wrowB + pt * 4);
      const int iA0 = (int)(short)(pkA.z & 0xffffu);
      const int iA1 = (int)(short)(pkA.z >> 16);
      const int iB0 = (int)(short)(pkB.z & 0xffffu);
      const int iB1 = (int)(short)(pkB.z >> 16);
      // issue all 4 independent loads first
      const f16x8 gA0 = *(const f16x8*)(vBA + (ptrdiff_t)iA0 * 64);
      const f16x8 gA1 = *(const f16x8*)(vBA + (ptrdiff_t)iA1 * 64);
      const f16x8 gB0 = *(const f16x8*)(vBB + (ptrdiff_t)iB0 * 64);
      const f16x8 gB1 = *(const f16x8*)(vBB + (ptrdiff_t)iB1 * 64);
      const float wA0 = side ? hi_f(pkA.x) : lo_f(pkA.x);
      const float wA1 = side ? hi_f(pkA.y) : lo_f(pkA.y);
      const float wB0 = side ? hi_f(pkB.x) : lo_f(pkB.x);
      const float wB1 = side ? hi_f(pkB.y) : lo_f(pkB.y);
#pragma unroll
      for (int c = 0; c < 8; ++c) accA[c] = fmaf((float)gA0[c], wA0, accA[c]);
#pragma unroll
      for (int c = 0; c < 8; ++c) accA[c] = fmaf((float)gA1[c], wA1, accA[c]);
#pragma unroll
      for (int c = 0; c < 8; ++c) accB[c] = fmaf((float)gB0[c], wB0, accB[c]);
#pragma unroll
      for (int c = 0; c < 8; ++c) accB[c] = fmaf((float)gB1[c], wB1, accB[c]);
    }

#pragma unroll
    for (int c = 0; c < 8; ++c) accA[c] += __shfl_xor(accA[c], 4);
#pragma unroll
    for (int c = 0; c < 8; ++c) accB[c] += __shfl_xor(accB[c], 4);

    if (g < 4) {
      const int qgA = q0 + (g0i >> 3), hA = g0i & 7;
      const int qgB = q0 + (g1i >> 3), hB = g1i & 7;
      const uint4 oA = make_uint4(pkrtz(accA[0], accA[1]), pkrtz(accA[2], accA[3]),
                                  pkrtz(accA[4], accA[5]), pkrtz(accA[6], accA[7]));
      *(uint4*)(samp + (size_t)qgA * 256 + hA * 32 + g * 8) = oA;
      const uint4 oB = make_uint4(pkrtz(accB[0], accB[1]), pkrtz(accB[2], accB[3]),
                                  pkrtz(accB[4], accB[5]), pkrtz(accB[6], accB[7]));
      *(uint4*)(samp + (size_t)qgB * 256 + hB * 32 + g * 8) = oB;
    }
  }
}

extern "C" void kernel_launch(void* const* d_in, const int* in_sizes, int n_in,
                              void* d_out, int out_size, void* d_ws, size_t ws_size,
                              hipStream_t stream) {
  const float* query         = (const float*)d_in[0];
  const float* ref_pts       = (const float*)d_in[1];
  const float* input_flatten = (const float*)d_in[2];
  const int*   sshapes       = (const int*)d_in[3];
  const int*   lstart        = (const int*)d_in[4];
  const float* w_val  = (const float*)d_in[5];
  const float* b_val  = (const float*)d_in[6];
  const float* w_off  = (const float*)d_in[7];
  const float* b_off  = (const float*)d_in[8];
  const float* w_attn = (const float*)d_in[9];
  const float* b_attn = (const float*)d_in[10];
  const float* w_out  = (const float*)d_in[11];
  const float* b_out  = (const float*)d_in[12];
  float* out = (float*)d_out;

  char* ws = (char*)d_ws;
  unsigned short* guard_pre  = (unsigned short*)(ws);             //        128 zeroed
  unsigned short* valb   = (unsigned short*)(ws + 128);           // 11,141,120 [B*8][LV][32] f16
  unsigned short* guard_post = (unsigned short*)(ws + 11141248);  //        128 zeroed
  unsigned short* samp   = (unsigned short*)(ws + 11141376);      // 11,141,120 [M,256] f16
  unsigned short* offb   = (unsigned short*)(ws + 22282496);      // 11,141,120 [M,256] f16
  unsigned short* logitb = (unsigned short*)(ws + 33423616);      //  5,570,560 [M,128] f16
  unsigned short* Wcat   = (unsigned short*)(ws + 38994176);      //    196,608 [384][256] f16
  unsigned short* Wo     = (unsigned short*)(ws + 39190784);      //    131,072 [256][256] f16
  unsigned short* Wvt    = (unsigned short*)(ws + 39321856);      //    131,072 [256][256] f16

  dim3 blk(256);
  conv_weights<<<dim3(4, 14), blk, 0, stream>>>(
      w_off, w_out, w_val, w_attn, Wcat, Wo, Wvt, guard_pre, guard_post);
  gemm_front<<<dim3(880), blk, 0, stream>>>(
      input_flatten, query, Wvt, Wcat, b_val, b_off, b_attn, valb, offb, logitb);
  msda_sample_v18<<<dim3(M_TOT / 8), blk, 0, stream>>>(
      offb, logitb, valb, ref_pts, sshapes, lstart, samp);
  gemm_out64<<<dim3(680), blk, 0, stream>>>(samp, Wo, b_out, out);
}

// Round 22
// 72.679 us; speedup vs baseline: 1.0236x; 1.0236x over previous
//
#include <hip/hip_runtime.h>
#include <hip/hip_fp16.h>
#include <math.h>

#define LQ 5440
#define LV 5440
#define BATCH_ 4
#define M_TOT (BATCH_ * LQ)   // 21760

typedef _Float16 f16x8 __attribute__((ext_vector_type(8)));
typedef _Float16 f16x2t __attribute__((ext_vector_type(2)));
typedef float f32x4 __attribute__((ext_vector_type(4)));
typedef unsigned int uint_t;

__device__ __forceinline__ uint_t f2h2(float a, float b) {   // pack 2 f32 -> f16x2 (RNE)
  const unsigned short ua = __half_as_ushort(__float2half(a));
  const unsigned short ub = __half_as_ushort(__float2half(b));
  return (uint_t)ua | ((uint_t)ub << 16);
}
__device__ __forceinline__ uint_t pkrtz(float a, float b) {  // HW packed f32->f16 (RTZ)
  auto r = __builtin_amdgcn_cvt_pkrtz(a, b);
  uint_t u;
  __builtin_memcpy(&u, &r, 4);
  return u;
}
__device__ __forceinline__ float lo_f(uint_t u) {
  f16x2t h; __builtin_memcpy(&h, &u, 4); return (float)h[0];
}
__device__ __forceinline__ float hi_f(uint_t u) {
  f16x2t h; __builtin_memcpy(&h, &u, 4); return (float)h[1];
}

// ---------------- weight conversion (transpose + f16) + valb guard zeroing ----------------
__global__ __launch_bounds__(256) void conv_weights(
    const float* __restrict__ w_off, const float* __restrict__ w_out,
    const float* __restrict__ w_val, const float* __restrict__ w_attn,
    unsigned short* __restrict__ Wcat, unsigned short* __restrict__ Wo,
    unsigned short* __restrict__ Wvt,
    unsigned short* __restrict__ guard_pre, unsigned short* __restrict__ guard_post)
{
  __shared__ float tbuf[64][65];
  const int tid = threadIdx.x;
  if (blockIdx.x == 0 && blockIdx.y == 0 && tid < 64) {
    guard_pre[tid] = 0;
    guard_post[tid] = 0;
  }
  const int k0 = blockIdx.x * 64;
  const int yy = blockIdx.y;
  const float* src; unsigned short* dst; int N; int ntile; int roff = 0;
  if (yy < 4)       { src = w_off;  dst = Wcat; N = 256; ntile = yy; }
  else if (yy < 8)  { src = w_out;  dst = Wo;   N = 256; ntile = yy - 4; }
  else if (yy < 12) { src = w_val;  dst = Wvt;  N = 256; ntile = yy - 8; }
  else              { src = w_attn; dst = Wcat; N = 128; ntile = yy - 12; roff = 256; }
  const int n0 = ntile * 64;
#pragma unroll
  for (int i = 0; i < 16; ++i) {
    const int r = (tid >> 6) + i * 4;
    const int c = tid & 63;
    tbuf[r][c] = src[(size_t)(k0 + r) * N + n0 + c];
  }
  __syncthreads();
#pragma unroll
  for (int i = 0; i < 16; ++i) {
    const int n = (tid >> 6) + i * 4;
    const int kk = tid & 63;
    dst[(size_t)(roff + n0 + n) * 256 + k0 + kk] =
        __half_as_ushort(__float2half(tbuf[kk][n]));
  }
}

// ---------------- front GEMM: value(head-major out) + off/logit fused, XCD-grouped ----------
__global__ __launch_bounds__(256) void gemm_front(
    const float* __restrict__ ifl, const float* __restrict__ query,
    const unsigned short* __restrict__ Wvt, const unsigned short* __restrict__ Wcat,
    const float* __restrict__ b_val, const float* __restrict__ b_off,
    const float* __restrict__ b_attn,
    unsigned short* __restrict__ valb, unsigned short* __restrict__ offb,
    unsigned short* __restrict__ logitb)
{
  const int P = blockIdx.x;
  const int X = P & 7;
  const int j = P >> 3;
  const int p = j % 5;
  const int rblk = X * 22 + j / 5;
  if (rblk >= M_TOT / 128) return;

  __shared__ unsigned short Sh[2][128 * 64];
  unsigned short* As = Sh[0];
  unsigned short* Bs = Sh[1];
  const int tid = threadIdx.x;
  const int w = tid >> 6, lane = tid & 63;
  const int wm = w >> 1, wn = w & 1;
  const int lr = lane & 15, lk = lane >> 4;
  const bool isval = p < 2;
  const float* Af = isval ? ifl : query;
  const unsigned short* Bt = isval ? Wvt : Wcat;
  const int n0 = (isval ? p : p - 2) * 128;
  const int m0 = rblk * 128;

  f32x4 acc[4][4] = {};

  for (int t = 0; t < 4; ++t) {
    const int ka = t * 64;
#pragma unroll
    for (int i = 0; i < 4; ++i) {
      const int rbase = i * 32 + w * 8;
      const int row = rbase + (lane >> 3);
      const int slot = lane & 7;
      const int gs = slot ^ (row & 7);                 // inverse-swizzle SOURCE (rule 21)
      const unsigned short* gp = Bt + (size_t)(n0 + row) * 256 + ka + gs * 8;
      __builtin_amdgcn_global_load_lds(
          (const __attribute__((address_space(1))) uint_t*)gp,
          (__attribute__((address_space(3))) uint_t*)(Bs + rbase * 64), 16, 0, 0);
    }
#pragma unroll
    for (int i = 0; i < 4; ++i) {
      const int rbase = i * 32 + w * 8;
      const int row = rbase + (lane >> 3);
      const int slot = lane & 7;
      const int gs = slot ^ (row & 7);
      const float* gp = Af + (size_t)(m0 + row) * 256 + ka + gs * 8;
      const float4 a0 = *(const float4*)gp;
      const float4 a1 = *(const float4*)(gp + 4);
      *(uint4*)&As[(size_t)row * 64 + slot * 8] =
          make_uint4(pkrtz(a0.x, a0.y), pkrtz(a0.z, a0.w),
                     pkrtz(a1.x, a1.y), pkrtz(a1.z, a1.w));
    }
    asm volatile("s_waitcnt vmcnt(0)" ::: "memory");
    __syncthreads();
#pragma unroll
    for (int kk = 0; kk < 2; ++kk) {
      f16x8 af[4], bfv[4];
#pragma unroll
      for (int m = 0; m < 4; ++m) {
        const int row = wm * 64 + m * 16 + lr;
        const int so = (kk * 4 + lk) ^ (row & 7);      // swizzled read
        af[m] = *(const f16x8*)((const char*)As + row * 128 + so * 16);
      }
#pragma unroll
      for (int n = 0; n < 4; ++n) {
        const int row = wn * 64 + n * 16 + lr;
        const int so = (kk * 4 + lk) ^ (row & 7);
        bfv[n] = *(const f16x8*)((const char*)Bs + row * 128 + so * 16);
      }
#pragma unroll
      for (int m = 0; m < 4; ++m)
#pragma unroll
        for (int n = 0; n < 4; ++n)
          acc[m][n] = __builtin_amdgcn_mfma_f32_16x16x32_f16(af[m], bfv[n], acc[m][n], 0, 0, 0);
    }
    __syncthreads();
  }

  if (!isval) {
#pragma unroll
    for (int n = 0; n < 4; ++n) {
      const int col = n0 + wn * 64 + n * 16 + lr;
      const float bv = (col < 256) ? b_off[col] : b_attn[col - 256];
#pragma unroll
      for (int m = 0; m < 4; ++m) {
        const int rbase = m0 + wm * 64 + m * 16 + lk * 4;
#pragma unroll
        for (int j2 = 0; j2 < 4; ++j2) {
          const float v = acc[m][n][j2] + bv;
          const int row = rbase + j2;
          const unsigned short hv = __half_as_ushort(__float2half(v));
          if (col < 256) offb[(size_t)row * 256 + col] = hv;
          else           logitb[(size_t)row * 128 + (col - 256)] = hv;
        }
      }
    }
  } else {
    // head-major epilogue via LDS transpose
    unsigned short* Sb = &Sh[0][0];                 // 32 KB
#pragma unroll
    for (int n = 0; n < 4; ++n) {
      const int lcol = wn * 64 + n * 16 + lr;
      const float bv = b_val[n0 + lcol];
#pragma unroll
      for (int m = 0; m < 4; ++m) {
        const int lrow = wm * 64 + m * 16 + lk * 4;
#pragma unroll
        for (int j2 = 0; j2 < 4; ++j2)
          Sb[(size_t)(lrow + j2) * 128 + lcol] =
              __half_as_ushort(__float2half(acc[m][n][j2] + bv));
      }
    }
    __syncthreads();
#pragma unroll
    for (int it = 0; it < 8; ++it) {
      const int idx = it * 256 + tid;
      const int r  = idx >> 4;
      const int c8 = idx & 15;
      const uint_t row_g = (uint_t)(m0 + r);
      const uint_t bb  = row_g / (uint_t)LV;
      const uint_t pos = row_g - bb * (uint_t)LV;
      const int colg = n0 + c8 * 8;
      const uint_t hh = (uint_t)colg >> 5;
      const uint_t ch = (uint_t)colg & 31u;
      unsigned short* dp = valb + (((size_t)(bb * 8u + hh) * LV + pos) << 5) + ch;
      *(uint4*)dp = *(const uint4*)&Sb[(size_t)r * 128 + c8 * 8];
    }
  }
}

// ---------------- out GEMM: BM=64 x BN=128, 680 blocks, XCD-chunked ----------------
__global__ __launch_bounds__(256) void gemm_out64(
    const unsigned short* __restrict__ A,    // samp f16 [M,256]
    const unsigned short* __restrict__ Bt,   // Wo f16 [256][256]
    const float* __restrict__ bias,
    float* __restrict__ C)
{
  const int P = blockIdx.x;
  const int G = (P & 7) * 85 + (P >> 3);
  const int p = G & 1;
  const int rblk = G >> 1;

  __shared__ unsigned short As[64 * 64];
  __shared__ unsigned short Bs[128 * 64];
  const int tid = threadIdx.x;
  const int w = tid >> 6, lane = tid & 63;
  const int wm = w & 1, wn = w >> 1;         // wave tile: 32 rows x 64 cols
  const int lr = lane & 15, lk = lane >> 4;
  const int m0 = rblk * 64, n0 = p * 128;

  f32x4 acc[2][4] = {};

  for (int t = 0; t < 4; ++t) {
    const int ka = t * 64;
#pragma unroll
    for (int i = 0; i < 2; ++i) {
      const int rbase = i * 32 + w * 8;
      const int row = rbase + (lane >> 3);
      const int slot = lane & 7;
      const int gs = slot ^ (row & 7);
      const unsigned short* gp = A + (size_t)(m0 + row) * 256 + ka + gs * 8;
      __builtin_amdgcn_global_load_lds(
          (const __attribute__((address_space(1))) uint_t*)gp,
          (__attribute__((address_space(3))) uint_t*)(As + rbase * 64), 16, 0, 0);
    }
#pragma unroll
    for (int i = 0; i < 4; ++i) {
      const int rbase = i * 32 + w * 8;
      const int row = rbase + (lane >> 3);
      const int slot = lane & 7;
      const int gs = slot ^ (row & 7);
      const unsigned short* gp = Bt + (size_t)(n0 + row) * 256 + ka + gs * 8;
      __builtin_amdgcn_global_load_lds(
          (const __attribute__((address_space(1))) uint_t*)gp,
          (__attribute__((address_space(3))) uint_t*)(Bs + rbase * 64), 16, 0, 0);
    }
    asm volatile("s_waitcnt vmcnt(0)" ::: "memory");
    __syncthreads();
#pragma unroll
    for (int kk = 0; kk < 2; ++kk) {
      f16x8 af[2], bfv[4];
#pragma unroll
      for (int m = 0; m < 2; ++m) {
        const int row = wm * 32 + m * 16 + lr;
        const int so = (kk * 4 + lk) ^ (row & 7);
        af[m] = *(const f16x8*)((const char*)As + row * 128 + so * 16);
      }
#pragma unroll
      for (int n = 0; n < 4; ++n) {
        const int row = wn * 64 + n * 16 + lr;
        const int so = (kk * 4 + lk) ^ (row & 7);
        bfv[n] = *(const f16x8*)((const char*)Bs + row * 128 + so * 16);
      }
#pragma unroll
      for (int m = 0; m < 2; ++m)
#pragma unroll
        for (int n = 0; n < 4; ++n)
          acc[m][n] = __builtin_amdgcn_mfma_f32_16x16x32_f16(af[m], bfv[n], acc[m][n], 0, 0, 0);
    }
    __syncthreads();
  }
#pragma unroll
  for (int n = 0; n < 4; ++n) {
    const int col = n0 + wn * 64 + n * 16 + lr;
    const float bv = bias[col];
#pragma unroll
    for (int m = 0; m < 2; ++m) {
      const int rbase = m0 + wm * 32 + m * 16 + lk * 4;
#pragma unroll
      for (int j2 = 0; j2 < 4; ++j2)
        C[(size_t)(rbase + j2) * 256 + col] = acc[m][n][j2] + bv;
    }
  }
}

// ---------------- sampler v17: 8 queries/block, 8-lane groups, 128B x-pair loads --------
// value [B*8][LV][32] f16; 2 sequential gather groups/thread.
// L = ((P&7)>>1)*680 + (P&1)*340 + (P>>3), bijective for P in [0,2720): batch b -> XCDs {2b,2b+1}.
__global__ __launch_bounds__(256) void msda_sample_v17(
    const unsigned short* __restrict__ off_buf,   // [M,256] f16
    const unsigned short* __restrict__ logit_buf, // [M,128] f16
    const unsigned short* __restrict__ value,     // [B*8][LV][32] f16
    const float* __restrict__ ref_pts,            // [B,LQ,4,2]
    const int*  __restrict__ sshapes, const int* __restrict__ lstart,
    unsigned short* __restrict__ samp)            // [M,256] f16
{
  __shared__ uint_t wlds[64 * 68];                // 17,408 B
  const int tid = threadIdx.x;
  const int P  = blockIdx.x;
  const int L  = (((P & 7) >> 1) * 680) + ((P & 1) * 340) + (P >> 3);
  const int q0 = L * 8;
  const int b  = L / (LQ / 8);

  // ---------- phase 1: 256 tasks = (q0..q7, h, l), one per thread ----------
  {
    const int q  = tid >> 5;
    const int h  = (tid >> 2) & 7;
    const int l  = tid & 3;
    const int qg = q0 + q;
    const int Hl = sshapes[2 * l], Wl = sshapes[2 * l + 1];
    const int st = lstart[l];
    const float rx = ref_pts[(size_t)qg * 8 + l * 2 + 0];
    const float ry = ref_pts[(size_t)qg * 8 + l * 2 + 1];
    const float fx = rx * (float)Wl - 0.5f;
    const float fy = ry * (float)Hl - 0.5f;

    const uint4 og = *(const uint4*)(off_buf + (size_t)qg * 256 + h * 32 + l * 8);
    const float offv[8] = {lo_f(og.x), hi_f(og.x), lo_f(og.y), hi_f(og.y),
                           lo_f(og.z), hi_f(og.z), lo_f(og.w), hi_f(og.w)};

    const uint2 lgu = *(const uint2*)(logit_buf + (size_t)qg * 128 + h * 16 + l * 4);
    float lg[4];
    lg[0] = lo_f(lgu.x); lg[1] = hi_f(lgu.x);
    lg[2] = lo_f(lgu.y); lg[3] = hi_f(lgu.y);

    float mx = fmaxf(fmaxf(lg[0], lg[1]), fmaxf(lg[2], lg[3]));
    mx = fmaxf(mx, __shfl_xor(mx, 1));
    mx = fmaxf(mx, __shfl_xor(mx, 2));
    float ex[4]; float ssum = 0.f;
#pragma unroll
    for (int p = 0; p < 4; ++p) { ex[p] = __expf(lg[p] - mx); ssum += ex[p]; }
    ssum += __shfl_xor(ssum, 1);
    ssum += __shfl_xor(ssum, 2);
    const float inv = 1.f / ssum;

    uint_t* wrow = wlds + (size_t)(q * 8 + h) * 68;

#pragma unroll
    for (int p = 0; p < 4; ++p) {
      const float x = fx + offv[p * 2 + 0];
      const float y = fy + offv[p * 2 + 1];
      const float aw = ex[p] * inv;
      const float xf = floorf(x), yf = floorf(y);
      const int x0i = (int)xf, y0i = (int)yf;
      const float wx1 = x - xf, wy1 = y - yf;
      const float wx0 = 1.f - wx1, wy0 = 1.f - wy1;
      const int x1i = x0i + 1, y1i = y0i + 1;
      const bool vx0 = (uint_t)x0i < (uint_t)Wl, vx1 = (uint_t)x1i < (uint_t)Wl;
      const bool vy0 = (uint_t)y0i < (uint_t)Hl, vy1 = (uint_t)y1i < (uint_t)Hl;
      const float awy0 = aw * wy0, awy1 = aw * wy1;
      const float w00 = (vy0 && vx0) ? awy0 * wx0 : 0.f;
      const float w01 = (vy0 && vx1) ? awy0 * wx1 : 0.f;
      const float w10 = (vy1 && vx0) ? awy1 * wx0 : 0.f;
      const float w11 = (vy1 && vx1) ? awy1 * wx1 : 0.f;
      const int yc0 = min(max(y0i, 0), Hl - 1);
      const int yc1 = min(max(y1i, 0), Hl - 1);
      const int xr  = (vx0 || vx1) ? max(x0i, -1) : 0;
      const int i00 = st + yc0 * Wl + xr;          // in [-1, LV-1]
      const int i10 = st + yc1 * Wl + xr;
      uint4 pk;
      pk.x = f2h2(w00, w01);
      pk.y = f2h2(w10, w11);
      pk.z = ((uint_t)i00 & 0xffffu) | (((uint_t)i10 & 0xffffu) << 16);
      pk.w = 0u;
      *(uint4*)(wrow + (l * 4 + p) * 4) = pk;
    }
  }
  __syncthreads();

  // ---------- phase 2: 64 groups x 8 lanes, 2 sequential per thread ----------
  {
    const int g    = tid & 7;
    const int side = g >> 2;
#pragma unroll
    for (int gi = 0; gi < 2; ++gi) {
      const int grp = gi * 32 + (tid >> 3);        // 0..63
      const int q2  = grp >> 3;
      const int h2  = grp & 7;
      const int qg2 = q0 + q2;
      const uint_t* wrow = wlds + (size_t)grp * 68;
      const char* vB = (const char*)value
          + ((size_t)(b * 8 + h2) * LV) * 64 + (size_t)g * 16;
      float acc[8] = {};
#pragma unroll
      for (int pt = 0; pt < 16; ++pt) {
        const uint4 pk = *(const uint4*)(wrow + pt * 4);
        const float wA = side ? hi_f(pk.x) : lo_f(pk.x);
        const float wB = side ? hi_f(pk.y) : lo_f(pk.y);
        const int i0 = (int)(short)(pk.z & 0xffffu);
        const int i1 = (int)(short)(pk.z >> 16);
        const f16x8 g0 = *(const f16x8*)(vB + (ptrdiff_t)i0 * 64);
        const f16x8 g1 = *(const f16x8*)(vB + (ptrdiff_t)i1 * 64);
#pragma unroll
        for (int c = 0; c < 8; ++c) acc[c] = fmaf((float)g0[c], wA, acc[c]);
#pragma unroll
        for (int c = 0; c < 8; ++c) acc[c] = fmaf((float)g1[c], wB, acc[c]);
      }
#pragma unroll
      for (int c = 0; c < 8; ++c) acc[c] += __shfl_xor(acc[c], 4);
      if (g < 4) {
        const uint4 o = make_uint4(pkrtz(acc[0], acc[1]), pkrtz(acc[2], acc[3]),
                                   pkrtz(acc[4], acc[5]), pkrtz(acc[6], acc[7]));
        *(uint4*)(samp + (size_t)qg2 * 256 + h2 * 32 + g * 8) = o;
      }
    }
  }
}

extern "C" void kernel_launch(void* const* d_in, const int* in_sizes, int n_in,
                              void* d_out, int out_size, void* d_ws, size_t ws_size,
                              hipStream_t stream) {
  const float* query         = (const float*)d_in[0];
  const float* ref_pts       = (const float*)d_in[1];
  const float* input_flatten = (const float*)d_in[2];
  const int*   sshapes       = (const int*)d_in[3];
  const int*   lstart        = (const int*)d_in[4];
  const float* w_val  = (const float*)d_in[5];
  const float* b_val  = (const float*)d_in[6];
  const float* w_off  = (const float*)d_in[7];
  const float* b_off  = (const float*)d_in[8];
  const float* w_attn = (const float*)d_in[9];
  const float* b_attn = (const float*)d_in[10];
  const float* w_out  = (const float*)d_in[11];
  const float* b_out  = (const float*)d_in[12];
  float* out = (float*)d_out;

  char* ws = (char*)d_ws;
  unsigned short* guard_pre  = (unsigned short*)(ws);             //        128 zeroed
  unsigned short* valb   = (unsigned short*)(ws + 128);           // 11,141,120 [B*8][LV][32] f16
  unsigned short* guard_post = (unsigned short*)(ws + 11141248);  //        128 zeroed
  unsigned short* samp   = (unsigned short*)(ws + 11141376);      // 11,141,120 [M,256] f16
  unsigned short* offb   = (unsigned short*)(ws + 22282496);      // 11,141,120 [M,256] f16
  unsigned short* logitb = (unsigned short*)(ws + 33423616);      //  5,570,560 [M,128] f16
  unsigned short* Wcat   = (unsigned short*)(ws + 38994176);      //    196,608 [384][256] f16
  unsigned short* Wo     = (unsigned short*)(ws + 39190784);      //    131,072 [256][256] f16
  unsigned short* Wvt    = (unsigned short*)(ws + 39321856);      //    131,072 [256][256] f16

  dim3 blk(256);
  conv_weights<<<dim3(4, 14), blk, 0, stream>>>(
      w_off, w_out, w_val, w_attn, Wcat, Wo, Wvt, guard_pre, guard_post);
  gemm_front<<<dim3(880), blk, 0, stream>>>(
      input_flatten, query, Wvt, Wcat, b_val, b_off, b_attn, valb, offb, logitb);
  msda_sample_v17<<<dim3(M_TOT / 8), blk, 0, stream>>>(
      offb, logitb, valb, ref_pts, sshapes, lstart, samp);
  gemm_out64<<<dim3(680), blk, 0, stream>>>(samp, Wo, b_out, out);
}